// Round 2
// baseline (17963.972 us; speedup 1.0000x reference)
//
#include <hip/hip_runtime.h>
#include <hip/hip_bf16.h>
#include <math.h>

// ---- problem constants (BERT-base, B=8, S=512) ----
#define S_LEN   512
#define HID     768
#define NLAYER  12
#define NHEAD   12
#define FFN_DIM 3072
#define HDIM    64
#define NTOK    4096   // B*S

// ---------------------------------------------------------------------------
// block-wide reduction of (sum, sumsq) over 256 threads (4 waves of 64)
// ---------------------------------------------------------------------------
__device__ __forceinline__ void block_reduce_2(float& sum, float& sq) {
  __shared__ float sd[8];
  int lane = threadIdx.x & 63;
  int wid  = threadIdx.x >> 6;
  #pragma unroll
  for (int off = 32; off > 0; off >>= 1) {
    sum += __shfl_down(sum, off, 64);
    sq  += __shfl_down(sq,  off, 64);
  }
  if (lane == 0) { sd[wid] = sum; sd[4 + wid] = sq; }
  __syncthreads();
  sum = sd[0] + sd[1] + sd[2] + sd[3];
  sq  = sd[4] + sd[5] + sd[6] + sd[7];
}

// ---------------------------------------------------------------------------
// mask bias: -10000 where input_id == 0 (padding), else 0
// ---------------------------------------------------------------------------
__global__ __launch_bounds__(256) void mask_kernel(const int* __restrict__ ids,
                                                   float* __restrict__ mb) {
  int i = blockIdx.x * 256 + threadIdx.x;
  if (i < NTOK) mb[i] = (ids[i] == 0) ? -10000.0f : 0.0f;
}

// ---------------------------------------------------------------------------
// embeddings + layernorm: one block per token, 256 threads, 3 elems/thread
// ---------------------------------------------------------------------------
__global__ __launch_bounds__(256) void embed_ln_kernel(
    const int* __restrict__ ids, const int* __restrict__ tids,
    const float* __restrict__ we, const float* __restrict__ pe,
    const float* __restrict__ te, const float* __restrict__ gamma,
    const float* __restrict__ beta, float* __restrict__ out) {
  int t = blockIdx.x;
  int s = t & (S_LEN - 1);
  int id = ids[t];
  int tp = tids[t];
  float x[3];
  #pragma unroll
  for (int i = 0; i < 3; ++i) {
    int c = threadIdx.x + i * 256;
    x[i] = we[(size_t)id * HID + c] + pe[(size_t)s * HID + c] +
           te[(size_t)tp * HID + c];
  }
  float sum = x[0] + x[1] + x[2];
  float sq  = x[0]*x[0] + x[1]*x[1] + x[2]*x[2];
  block_reduce_2(sum, sq);
  float mu   = sum * (1.0f / HID);
  float var  = sq * (1.0f / HID) - mu * mu;
  float rstd = rsqrtf(var + 1e-12f);
  #pragma unroll
  for (int i = 0; i < 3; ++i) {
    int c = threadIdx.x + i * 256;
    out[(size_t)t * HID + c] = (x[i] - mu) * rstd * gamma[c] + beta[c];
  }
}

// ---------------------------------------------------------------------------
// residual add + layernorm: out = LN(a + b) * gamma + beta  (in-place safe)
// ---------------------------------------------------------------------------
__global__ __launch_bounds__(256) void add_ln_kernel(
    const float* __restrict__ a, const float* __restrict__ b,
    const float* __restrict__ gamma, const float* __restrict__ beta,
    float* __restrict__ out) {
  int t = blockIdx.x;
  float x[3];
  #pragma unroll
  for (int i = 0; i < 3; ++i) {
    int c = threadIdx.x + i * 256;
    size_t idx = (size_t)t * HID + c;
    x[i] = a[idx] + b[idx];
  }
  float sum = x[0] + x[1] + x[2];
  float sq  = x[0]*x[0] + x[1]*x[1] + x[2]*x[2];
  block_reduce_2(sum, sq);
  float mu   = sum * (1.0f / HID);
  float var  = sq * (1.0f / HID) - mu * mu;
  float rstd = rsqrtf(var + 1e-12f);
  #pragma unroll
  for (int i = 0; i < 3; ++i) {
    int c = threadIdx.x + i * 256;
    out[(size_t)t * HID + c] = (x[i] - mu) * rstd * gamma[c] + beta[c];
  }
}

// ---------------------------------------------------------------------------
// fp32 GEMM: C[M,N] = A[M,K] @ B[K,N] + bias[N], optional exact GELU.
// 64x64 tile, KT=16, 256 threads, 4x4 register tile.
// LDS rows padded to 68 floats (272 B): keeps float4 alignment, <=2-way banks.
// M%64==0, N%64==0, K%16==0 hold for all call sites (no bounds checks).
// ---------------------------------------------------------------------------
template <int GELU>
__global__ __launch_bounds__(256) void gemm_kernel(
    const float* __restrict__ A, const float* __restrict__ B,
    const float* __restrict__ bias, float* __restrict__ C,
    int M, int N, int K) {
  __shared__ __align__(16) float As[16][68];  // [k][m]
  __shared__ __align__(16) float Bs[16][68];  // [k][n]
  int tid = threadIdx.x;
  int m0 = blockIdx.y * 64;
  int n0 = blockIdx.x * 64;
  int tx = tid & 15;   // -> 4 output cols
  int ty = tid >> 4;   // -> 4 output rows
  float acc[4][4] = {};

  int ak = tid & 15;   // k for A load
  int am = tid >> 4;   // m base for A load (0..15, stride 16)
  int bn = tid & 63;   // n for B load
  int bk_ = tid >> 6;  // k base for B load (0..3, stride 4)
  const float* Aptr = A + (size_t)(m0 + am) * K + ak;
  const float* Bptr = B + (size_t)bk_ * N + n0 + bn;

  for (int kt = 0; kt < K; kt += 16) {
    #pragma unroll
    for (int i = 0; i < 4; ++i)
      As[ak][am + i * 16] = Aptr[(size_t)(i * 16) * K + kt];
    #pragma unroll
    for (int i = 0; i < 4; ++i)
      Bs[bk_ + i * 4][bn] = Bptr[(size_t)(kt + i * 4) * N];
    __syncthreads();
    #pragma unroll
    for (int kk = 0; kk < 16; ++kk) {
      float4 av = *(const float4*)&As[kk][ty * 4];
      float4 bv = *(const float4*)&Bs[kk][tx * 4];
      float a_[4] = {av.x, av.y, av.z, av.w};
      float b_[4] = {bv.x, bv.y, bv.z, bv.w};
      #pragma unroll
      for (int i = 0; i < 4; ++i)
        #pragma unroll
        for (int j = 0; j < 4; ++j)
          acc[i][j] += a_[i] * b_[j];
    }
    __syncthreads();
  }

  float4 bb = *(const float4*)&bias[n0 + tx * 4];
  float bias4[4] = {bb.x, bb.y, bb.z, bb.w};
  #pragma unroll
  for (int i = 0; i < 4; ++i) {
    float4 o;
    float* op = (float*)&o;
    #pragma unroll
    for (int j = 0; j < 4; ++j) {
      float vv = acc[i][j] + bias4[j];
      if (GELU) vv = 0.5f * vv * (1.0f + erff(vv * 0.70710678118654752f));
      op[j] = vv;
    }
    *(float4*)&C[(size_t)(m0 + ty * 4 + i) * N + n0 + tx * 4] = o;
  }
}

// ---------------------------------------------------------------------------
// fused attention: one block per (batch, head, 16 q-rows).
// q/k/v layout: [B, S, H] with head hh at columns hh*64..hh*64+63 (no
// transpose ever materialized). Scores for the 16 q-rows live in LDS.
// ---------------------------------------------------------------------------
__global__ __launch_bounds__(256) void attn_kernel(
    const float* __restrict__ q, const float* __restrict__ k,
    const float* __restrict__ v, const float* __restrict__ mb,
    float* __restrict__ ctx) {
  __shared__ __align__(16) float Qs[16][64];
  __shared__ __align__(16) float Ks[64][68];
  __shared__ float P[16][520];
  int tid = threadIdx.x;
  int b  = blockIdx.z;
  int hh = blockIdx.y;
  int q0 = blockIdx.x * 16;
  size_t base = (size_t)b * S_LEN * HID + (size_t)hh * HDIM;

  // load + pre-scale Q tile (16x64)
  #pragma unroll
  for (int i = 0; i < 4; ++i) {
    int idx = tid + i * 256;
    int qi = idx >> 6, d = idx & 63;
    Qs[qi][d] = q[base + (size_t)(q0 + qi) * HID + d] * 0.125f;  // 1/sqrt(64)
  }
  __syncthreads();

  // logits: thread (qi, kj) over k-tiles of 64 staged in LDS
  int qi = tid >> 4, kj = tid & 15;
  for (int kt = 0; kt < 8; ++kt) {
    #pragma unroll
    for (int i = 0; i < 16; ++i) {
      int idx = tid + i * 256;
      int r = idx >> 6, d = idx & 63;
      Ks[r][d] = k[base + (size_t)(kt * 64 + r) * HID + d];
    }
    __syncthreads();
    #pragma unroll
    for (int it = 0; it < 4; ++it) {
      int kk = kj + it * 16;
      float dot = 0.f;
      #pragma unroll
      for (int d = 0; d < 64; ++d) dot += Qs[qi][d] * Ks[kk][d];
      P[qi][kt * 64 + kk] = dot + mb[b * S_LEN + kt * 64 + kk];
    }
    __syncthreads();
  }

  // softmax over each of the 16 rows; 16 threads per row (lane groups align)
  float mx = -1e30f;
  for (int j = kj; j < S_LEN; j += 16) mx = fmaxf(mx, P[qi][j]);
  #pragma unroll
  for (int off = 8; off > 0; off >>= 1) mx = fmaxf(mx, __shfl_xor(mx, off, 16));
  float sum = 0.f;
  for (int j = kj; j < S_LEN; j += 16) {
    float e = __expf(P[qi][j] - mx);
    P[qi][j] = e;
    sum += e;
  }
  #pragma unroll
  for (int off = 8; off > 0; off >>= 1) sum += __shfl_xor(sum, off, 16);
  float inv = 1.0f / sum;
  for (int j = kj; j < S_LEN; j += 16) P[qi][j] *= inv;
  __syncthreads();

  // ctx = P @ V: wave qg handles q-rows qg*4..qg*4+3, lane d is the column
  int d = tid & 63, qg = tid >> 6;
  float acc[4] = {0.f, 0.f, 0.f, 0.f};
  for (int kk2 = 0; kk2 < S_LEN; ++kk2) {
    float vv = v[base + (size_t)kk2 * HID + d];
    #pragma unroll
    for (int i = 0; i < 4; ++i) acc[i] += P[qg * 4 + i][kk2] * vv;
  }
  #pragma unroll
  for (int i = 0; i < 4; ++i)
    ctx[base + (size_t)(q0 + qg * 4 + i) * HID + d] = acc[i];
}

// ---------------------------------------------------------------------------
// launch
// ---------------------------------------------------------------------------
extern "C" void kernel_launch(void* const* d_in, const int* in_sizes, int n_in,
                              void* d_out, int out_size, void* d_ws, size_t ws_size,
                              hipStream_t stream) {
  const int*   input_ids = (const int*)d_in[0];
  const int*   type_ids  = (const int*)d_in[1];
  const float* word_emb  = (const float*)d_in[2];
  const float* pos_emb   = (const float*)d_in[3];
  const float* type_emb  = (const float*)d_in[4];
  const float* eln_s     = (const float*)d_in[5];
  const float* eln_b     = (const float*)d_in[6];
  const float* wq = (const float*)d_in[7];
  const float* bq = (const float*)d_in[8];
  const float* wk = (const float*)d_in[9];
  const float* bk = (const float*)d_in[10];
  const float* wv = (const float*)d_in[11];
  const float* bv = (const float*)d_in[12];
  const float* wo = (const float*)d_in[13];
  const float* bo = (const float*)d_in[14];
  const float* l1s = (const float*)d_in[15];
  const float* l1b = (const float*)d_in[16];
  const float* w1  = (const float*)d_in[17];
  const float* b1  = (const float*)d_in[18];
  const float* w2  = (const float*)d_in[19];
  const float* b2  = (const float*)d_in[20];
  const float* l2s = (const float*)d_in[21];
  const float* l2b = (const float*)d_in[22];

  // workspace layout (floats). buf_ffn aliases {buf_q,buf_k,buf_v,buf_c} —
  // FFN_DIM == 4*HID and q/k/v/ctx are dead by the time ffn1 runs. ~75.5 MB.
  float* ws = (float*)d_ws;
  const size_t TH = (size_t)NTOK * HID;
  float* h     = ws;
  float* buf_q = h     + TH;
  float* buf_k = buf_q + TH;
  float* buf_v = buf_k + TH;
  float* buf_c = buf_v + TH;
  float* buf_ffn = buf_q;       // NTOK*FFN_DIM == 4*TH
  float* tmp   = buf_c + TH;
  float* mb    = tmp   + TH;

  dim3 blk(256);
  mask_kernel<<<dim3(NTOK / 256), blk, 0, stream>>>(input_ids, mb);
  embed_ln_kernel<<<dim3(NTOK), blk, 0, stream>>>(
      input_ids, type_ids, word_emb, pos_emb, type_emb, eln_s, eln_b, h);

  dim3 g_hh(HID / 64, NTOK / 64);      // 12 x 64
  dim3 g_hf(FFN_DIM / 64, NTOK / 64);  // 48 x 64
  dim3 g_at(S_LEN / 16, NHEAD, 8);     // 32 x 12 x 8

  for (int l = 0; l < NLAYER; ++l) {
    size_t woff = (size_t)l * HID * HID;
    size_t boff = (size_t)l * HID;
    gemm_kernel<0><<<g_hh, blk, 0, stream>>>(h, wq + woff, bq + boff, buf_q, NTOK, HID, HID);
    gemm_kernel<0><<<g_hh, blk, 0, stream>>>(h, wk + woff, bk + boff, buf_k, NTOK, HID, HID);
    gemm_kernel<0><<<g_hh, blk, 0, stream>>>(h, wv + woff, bv + boff, buf_v, NTOK, HID, HID);
    attn_kernel<<<g_at, blk, 0, stream>>>(buf_q, buf_k, buf_v, mb, buf_c);
    gemm_kernel<0><<<g_hh, blk, 0, stream>>>(buf_c, wo + woff, bo + boff, tmp, NTOK, HID, HID);
    add_ln_kernel<<<dim3(NTOK), blk, 0, stream>>>(h, tmp, l1s + boff, l1b + boff, h);
    gemm_kernel<1><<<g_hf, blk, 0, stream>>>(
        h, w1 + (size_t)l * HID * FFN_DIM, b1 + (size_t)l * FFN_DIM, buf_ffn,
        NTOK, FFN_DIM, HID);
    gemm_kernel<0><<<g_hh, blk, 0, stream>>>(
        buf_ffn, w2 + (size_t)l * FFN_DIM * HID, b2 + boff, tmp, NTOK, HID, FFN_DIM);
    float* dst = (l == NLAYER - 1) ? (float*)d_out : h;
    add_ln_kernel<<<dim3(NTOK), blk, 0, stream>>>(h, tmp, l2s + boff, l2b + boff, dst);
  }
}

// Round 3
// 3116.822 us; speedup vs baseline: 5.7636x; 5.7636x over previous
//
#include <hip/hip_runtime.h>
#include <hip/hip_bf16.h>
#include <math.h>

// ---- problem constants (BERT-base, B=8, S=512) ----
#define S_LEN   512
#define HID     768
#define NLAYER  12
#define NHEAD   12
#define FFN_DIM 3072
#define HDIM    64
#define NTOK    4096   // B*S
#define QKVN    2304   // 3*HID

typedef __bf16 bf16x8 __attribute__((ext_vector_type(8)));
typedef float  f32x4  __attribute__((ext_vector_type(4)));
typedef unsigned short us8 __attribute__((ext_vector_type(8)));

#define MFMA16(a, b, c) __builtin_amdgcn_mfma_f32_16x16x32_bf16((a), (b), (c), 0, 0, 0)

// ---------------------------------------------------------------------------
// block-wide reduction of (sum, sumsq) over 256 threads (4 waves of 64)
// ---------------------------------------------------------------------------
__device__ __forceinline__ void block_reduce_2(float& sum, float& sq) {
  __shared__ float sd[8];
  int lane = threadIdx.x & 63;
  int wid  = threadIdx.x >> 6;
  #pragma unroll
  for (int off = 32; off > 0; off >>= 1) {
    sum += __shfl_down(sum, off, 64);
    sq  += __shfl_down(sq,  off, 64);
  }
  if (lane == 0) { sd[wid] = sum; sd[4 + wid] = sq; }
  __syncthreads();
  sum = sd[0] + sd[1] + sd[2] + sd[3];
  sq  = sd[4] + sd[5] + sd[6] + sd[7];
}

// ---------------------------------------------------------------------------
// mask bias: -10000 where input_id == 0 (padding), else 0
// ---------------------------------------------------------------------------
__global__ __launch_bounds__(256) void mask_kernel(const int* __restrict__ ids,
                                                   float* __restrict__ mb) {
  int i = blockIdx.x * 256 + threadIdx.x;
  if (i < NTOK) mb[i] = (ids[i] == 0) ? -10000.0f : 0.0f;
}

// ---------------------------------------------------------------------------
// embeddings + layernorm -> fp32 h and bf16 h
// ---------------------------------------------------------------------------
__global__ __launch_bounds__(256) void embed_ln_kernel(
    const int* __restrict__ ids, const int* __restrict__ tids,
    const float* __restrict__ we, const float* __restrict__ pe,
    const float* __restrict__ te, const float* __restrict__ gamma,
    const float* __restrict__ beta, float* __restrict__ out32,
    __bf16* __restrict__ out16) {
  int t = blockIdx.x;
  int s = t & (S_LEN - 1);
  int id = ids[t];
  int tp = tids[t];
  float x[3];
  #pragma unroll
  for (int i = 0; i < 3; ++i) {
    int c = threadIdx.x + i * 256;
    x[i] = we[(size_t)id * HID + c] + pe[(size_t)s * HID + c] +
           te[(size_t)tp * HID + c];
  }
  float sum = x[0] + x[1] + x[2];
  float sq  = x[0]*x[0] + x[1]*x[1] + x[2]*x[2];
  block_reduce_2(sum, sq);
  float mu   = sum * (1.0f / HID);
  float var  = sq * (1.0f / HID) - mu * mu;
  float rstd = rsqrtf(var + 1e-12f);
  #pragma unroll
  for (int i = 0; i < 3; ++i) {
    int c = threadIdx.x + i * 256;
    float v = (x[i] - mu) * rstd * gamma[c] + beta[c];
    out32[(size_t)t * HID + c] = v;
    out16[(size_t)t * HID + c] = (__bf16)v;
  }
}

// ---------------------------------------------------------------------------
// residual add + layernorm -> fp32 (residual stream / d_out) and bf16 copy
// ---------------------------------------------------------------------------
__global__ __launch_bounds__(256) void add_ln_kernel(
    const float* __restrict__ a, const float* __restrict__ b,
    const float* __restrict__ gamma, const float* __restrict__ beta,
    float* __restrict__ out32, __bf16* __restrict__ out16) {
  int t = blockIdx.x;
  float x[3];
  #pragma unroll
  for (int i = 0; i < 3; ++i) {
    int c = threadIdx.x + i * 256;
    size_t idx = (size_t)t * HID + c;
    x[i] = a[idx] + b[idx];
  }
  float sum = x[0] + x[1] + x[2];
  float sq  = x[0]*x[0] + x[1]*x[1] + x[2]*x[2];
  block_reduce_2(sum, sq);
  float mu   = sum * (1.0f / HID);
  float var  = sq * (1.0f / HID) - mu * mu;
  float rstd = rsqrtf(var + 1e-12f);
  #pragma unroll
  for (int i = 0; i < 3; ++i) {
    int c = threadIdx.x + i * 256;
    float v = (x[i] - mu) * rstd * gamma[c] + beta[c];
    out32[(size_t)t * HID + c] = v;
    out16[(size_t)t * HID + c] = (__bf16)v;
  }
}

// ---------------------------------------------------------------------------
// transpose + fp32->bf16: src [R][C] f32 -> dst [C][R] bf16. R,C % 32 == 0.
// ---------------------------------------------------------------------------
__global__ __launch_bounds__(256) void tcvt_kernel(
    const float* __restrict__ src, __bf16* __restrict__ dst, int R, int C) {
  __shared__ float tile[32][33];
  int c0 = blockIdx.x * 32, r0 = blockIdx.y * 32;
  int tx = threadIdx.x & 31, ty = threadIdx.x >> 5;  // ty 0..7
  #pragma unroll
  for (int i = 0; i < 4; ++i) {
    int r = ty + i * 8;
    tile[r][tx] = src[(size_t)(r0 + r) * C + c0 + tx];
  }
  __syncthreads();
  #pragma unroll
  for (int i = 0; i < 4; ++i) {
    int r = ty + i * 8;
    dst[(size_t)(c0 + r) * R + r0 + tx] = (__bf16)tile[tx][r];
  }
}

// ---------------------------------------------------------------------------
// V-transpose: qkv [tok][2304] (v at cols 1536..2303) -> vt [b][h][64][512]
// ---------------------------------------------------------------------------
__global__ __launch_bounds__(256) void vtrans_kernel(
    const __bf16* __restrict__ qkv, __bf16* __restrict__ vt) {
  __shared__ __bf16 tile[32][33];
  int bh = blockIdx.z;
  int b = bh / NHEAD, h = bh % NHEAD;
  int s0 = blockIdx.x * 32, d0 = blockIdx.y * 32;
  int tx = threadIdx.x & 31, ty = threadIdx.x >> 5;
  #pragma unroll
  for (int i = 0; i < 4; ++i) {
    int r = ty + i * 8;  // s
    tile[r][tx] = qkv[(size_t)(b * S_LEN + s0 + r) * QKVN + 2 * HID + h * HDIM + d0 + tx];
  }
  __syncthreads();
  #pragma unroll
  for (int i = 0; i < 4; ++i) {
    int r = ty + i * 8;  // d
    vt[((size_t)bh * HDIM + d0 + r) * S_LEN + s0 + tx] = tile[tx][r];
  }
}

// ---------------------------------------------------------------------------
// bf16 MFMA GEMM: C[M,N] = A[M,K]bf16 @ Bt[N,K]bf16^T + bias.
// 128x64 block tile, BK=64, 256 threads (4 waves, each 32 rows x 64 cols).
// MODE 0: f32 out; 1: bf16 out; 2: bf16 out + exact GELU.
// LDS row stride 72 bf16 (144 B): frag ds_read_b128 lands 2-way (free).
// ---------------------------------------------------------------------------
template <int MODE>
__global__ __launch_bounds__(256) void mfma_gemm(
    const __bf16* __restrict__ A, const __bf16* __restrict__ Bt,
    const float* __restrict__ bias, void* __restrict__ Cout,
    int M, int N, int K) {
  constexpr int LDT = 72;
  __shared__ __align__(16) __bf16 As[128 * LDT];
  __shared__ __align__(16) __bf16 Bs[64 * LDT];
  const int tid  = threadIdx.x;
  const int wv   = tid >> 6;
  const int lane = tid & 63;
  const int l15  = lane & 15, quad = lane >> 4;
  const int m0 = blockIdx.y * 128, n0 = blockIdx.x * 64;
  const int srow = tid >> 3, schk = tid & 7;  // staging: row base, 8-elem chunk

  f32x4 acc[2][4];
  const f32x4 z4 = {0.f, 0.f, 0.f, 0.f};
  #pragma unroll
  for (int i = 0; i < 2; ++i)
    #pragma unroll
    for (int j = 0; j < 4; ++j) acc[i][j] = z4;

  const __bf16* Ag = A  + (size_t)(m0 + srow) * K + schk * 8;
  const __bf16* Bg = Bt + (size_t)(n0 + srow) * K + schk * 8;

  for (int kt = 0; kt < K; kt += 64) {
    #pragma unroll
    for (int c = 0; c < 4; ++c)
      *(us8*)&As[(srow + c * 32) * LDT + schk * 8] =
          *(const us8*)(Ag + (size_t)(c * 32) * K + kt);
    #pragma unroll
    for (int c = 0; c < 2; ++c)
      *(us8*)&Bs[(srow + c * 32) * LDT + schk * 8] =
          *(const us8*)(Bg + (size_t)(c * 32) * K + kt);
    __syncthreads();
    #pragma unroll
    for (int kc = 0; kc < 2; ++kc) {
      bf16x8 af[2], bfr[4];
      #pragma unroll
      for (int rt = 0; rt < 2; ++rt)
        af[rt] = *(const bf16x8*)&As[(wv * 32 + rt * 16 + l15) * LDT + kc * 32 + quad * 8];
      #pragma unroll
      for (int ct = 0; ct < 4; ++ct)
        bfr[ct] = *(const bf16x8*)&Bs[(ct * 16 + l15) * LDT + kc * 32 + quad * 8];
      #pragma unroll
      for (int rt = 0; rt < 2; ++rt)
        #pragma unroll
        for (int ct = 0; ct < 4; ++ct)
          acc[rt][ct] = MFMA16(af[rt], bfr[ct], acc[rt][ct]);
    }
    __syncthreads();
  }

  #pragma unroll
  for (int rt = 0; rt < 2; ++rt) {
    int rbase = m0 + wv * 32 + rt * 16 + quad * 4;
    #pragma unroll
    for (int ct = 0; ct < 4; ++ct) {
      int col = n0 + ct * 16 + l15;
      float bv = bias[col];
      #pragma unroll
      for (int r = 0; r < 4; ++r) {
        float v = acc[rt][ct][r] + bv;
        if (MODE == 2) v = 0.5f * v * (1.0f + erff(v * 0.70710678118654752f));
        if (MODE == 0)
          ((float*)Cout)[(size_t)(rbase + r) * N + col] = v;
        else
          ((__bf16*)Cout)[(size_t)(rbase + r) * N + col] = (__bf16)v;
      }
    }
  }
}

// ---------------------------------------------------------------------------
// MFMA attention: block = (64 q-rows, head, batch); wave w owns 16 q-rows.
// QK^T frags load straight from global (contiguous-d == frag k-dim).
// Scores (16x512/wave) live in registers; exact softmax; P goes through a
// per-wave LDS buffer (C-layout write -> A-layout read); PV reads V^T frags
// straight from global (contiguous-s == frag k-dim).
// ---------------------------------------------------------------------------
__global__ __launch_bounds__(256) void attn_mfma(
    const __bf16* __restrict__ qkv,  // [tok][2304], q at +0, k at +768
    const __bf16* __restrict__ vt,   // [b][h][64][512]
    const float* __restrict__ mb,    // [B*S]
    __bf16* __restrict__ ctx) {      // [tok][768]
  constexpr int PLD = 264;  // P row stride (bf16): 16B-aligned, bank-friendly
  __shared__ __align__(16) __bf16 Plds[4][16 * PLD];
  const int tid = threadIdx.x;
  const int wv = tid >> 6, lane = tid & 63;
  const int l15 = lane & 15, quad = lane >> 4;
  const int b = blockIdx.z, hh = blockIdx.y, q0 = blockIdx.x * 64;
  const f32x4 z4 = {0.f, 0.f, 0.f, 0.f};

  // Q A-frags: m = l15 (q row), k = d
  size_t qoff = ((size_t)(b * S_LEN) + q0 + wv * 16 + l15) * QKVN + hh * HDIM;
  bf16x8 qa0 = *(const bf16x8*)(qkv + qoff + quad * 8);
  bf16x8 qa1 = *(const bf16x8*)(qkv + qoff + 32 + quad * 8);

  // QK^T: 32 score tiles of 16 kpos
  f32x4 sc[32];
  #pragma unroll
  for (int kt = 0; kt < 32; ++kt) {
    size_t koff = ((size_t)(b * S_LEN) + kt * 16 + l15) * QKVN + HID + hh * HDIM;
    bf16x8 kb0 = *(const bf16x8*)(qkv + koff + quad * 8);
    bf16x8 kb1 = *(const bf16x8*)(qkv + koff + 32 + quad * 8);
    f32x4 t = MFMA16(qa0, kb0, z4);
    sc[kt] = MFMA16(qa1, kb1, t);
  }

  // scale + mask + row max
  float mx[4] = {-1e30f, -1e30f, -1e30f, -1e30f};
  #pragma unroll
  for (int kt = 0; kt < 32; ++kt) {
    float mval = mb[b * S_LEN + kt * 16 + l15];
    #pragma unroll
    for (int r = 0; r < 4; ++r) {
      float x = sc[kt][r] * 0.125f + mval;
      sc[kt][r] = x;
      mx[r] = fmaxf(mx[r], x);
    }
  }
  #pragma unroll
  for (int m = 1; m < 16; m <<= 1)
    #pragma unroll
    for (int r = 0; r < 4; ++r) mx[r] = fmaxf(mx[r], __shfl_xor(mx[r], m, 64));

  float sm[4] = {0.f, 0.f, 0.f, 0.f};
  #pragma unroll
  for (int kt = 0; kt < 32; ++kt)
    #pragma unroll
    for (int r = 0; r < 4; ++r) {
      float e = __expf(sc[kt][r] - mx[r]);
      sc[kt][r] = e;
      sm[r] += e;
    }
  #pragma unroll
  for (int m = 1; m < 16; m <<= 1)
    #pragma unroll
    for (int r = 0; r < 4; ++r) sm[r] += __shfl_xor(sm[r], m, 64);
  float inv[4];
  #pragma unroll
  for (int r = 0; r < 4; ++r) inv[r] = 1.0f / sm[r];

  // PV with per-wave LDS round-trip for P (two halves of 256 kpos)
  __bf16* pbuf = &Plds[wv][0];
  const __bf16* vbase = vt + (size_t)(b * NHEAD + hh) * HDIM * S_LEN;
  f32x4 oc[4] = {z4, z4, z4, z4};
  #pragma unroll
  for (int half = 0; half < 2; ++half) {
    #pragma unroll
    for (int kt2 = 0; kt2 < 16; ++kt2) {
      int kt = half * 16 + kt2;
      #pragma unroll
      for (int r = 0; r < 4; ++r)
        pbuf[(quad * 4 + r) * PLD + kt2 * 16 + l15] = (__bf16)(sc[kt][r] * inv[r]);
    }
    #pragma unroll
    for (int kc = 0; kc < 8; ++kc) {
      bf16x8 pa = *(const bf16x8*)&pbuf[l15 * PLD + kc * 32 + quad * 8];
      int kbase = half * 256 + kc * 32;
      #pragma unroll
      for (int ct = 0; ct < 4; ++ct) {
        const __bf16* vp =
            vbase + (size_t)(ct * 16 + l15) * S_LEN + kbase + quad * 8;
        oc[ct] = MFMA16(pa, *(const bf16x8*)vp, oc[ct]);
      }
    }
  }

  // store ctx bf16 [tok][768]
  int orow = b * S_LEN + q0 + wv * 16 + quad * 4;
  #pragma unroll
  for (int ct = 0; ct < 4; ++ct) {
    int col = hh * HDIM + ct * 16 + l15;
    #pragma unroll
    for (int r = 0; r < 4; ++r)
      ctx[(size_t)(orow + r) * HID + col] = (__bf16)oc[ct][r];
  }
}

// ---------------------------------------------------------------------------
// launch
// ---------------------------------------------------------------------------
extern "C" void kernel_launch(void* const* d_in, const int* in_sizes, int n_in,
                              void* d_out, int out_size, void* d_ws, size_t ws_size,
                              hipStream_t stream) {
  const int*   input_ids = (const int*)d_in[0];
  const int*   type_ids  = (const int*)d_in[1];
  const float* word_emb  = (const float*)d_in[2];
  const float* pos_emb   = (const float*)d_in[3];
  const float* type_emb  = (const float*)d_in[4];
  const float* eln_s     = (const float*)d_in[5];
  const float* eln_b     = (const float*)d_in[6];
  const float* wq = (const float*)d_in[7];
  const float* bq = (const float*)d_in[8];
  const float* wk = (const float*)d_in[9];
  const float* bk = (const float*)d_in[10];
  const float* wv = (const float*)d_in[11];
  const float* bv = (const float*)d_in[12];
  const float* wo = (const float*)d_in[13];
  const float* bo = (const float*)d_in[14];
  const float* l1s = (const float*)d_in[15];
  const float* l1b = (const float*)d_in[16];
  const float* w1  = (const float*)d_in[17];
  const float* b1  = (const float*)d_in[18];
  const float* w2  = (const float*)d_in[19];
  const float* b2  = (const float*)d_in[20];
  const float* l2s = (const float*)d_in[21];
  const float* l2b = (const float*)d_in[22];

  // ---- workspace carve-up (~71 MB) ----
  char* p = (char*)d_ws;
  float*   h32    = (float*)p;            p += (size_t)NTOK * HID * 4;   // 12.58M
  float*   tmp32  = (float*)p;            p += (size_t)NTOK * HID * 4;   // 12.58M
  __bf16*  vT16   = (__bf16*)tmp32;       // alias: vT live only during attn
  __bf16*  h16    = (__bf16*)p;           p += (size_t)NTOK * HID * 2;   // 6.29M
  __bf16*  qkv16  = (__bf16*)p;           p += (size_t)NTOK * QKVN * 2;  // 18.87M
  __bf16*  ctx16  = (__bf16*)p;           p += (size_t)NTOK * HID * 2;   // 6.29M
  __bf16*  ffn16  = qkv16;                // alias qkv16+ctx16 (25.17M exactly)
  __bf16*  wT     = (__bf16*)p;           p += (size_t)QKVN * HID * 2;   // 3.54M
  __bf16*  woT    = (__bf16*)p;           p += (size_t)HID * HID * 2;    // 1.18M
  __bf16*  w1T    = (__bf16*)p;           p += (size_t)HID * FFN_DIM * 2;// 4.72M
  __bf16*  w2T    = (__bf16*)p;           p += (size_t)HID * FFN_DIM * 2;// 4.72M
  float*   qkvb   = (float*)p;            p += (size_t)QKVN * 4;
  float*   mb     = (float*)p;            p += (size_t)NTOK * 4;

  dim3 blk(256);
  mask_kernel<<<dim3(NTOK / 256), blk, 0, stream>>>(input_ids, mb);
  embed_ln_kernel<<<dim3(NTOK), blk, 0, stream>>>(
      input_ids, type_ids, word_emb, pos_emb, type_emb, eln_s, eln_b, h32, h16);

  dim3 g_qkv(QKVN / 64, NTOK / 128);   // 36 x 32
  dim3 g_hh(HID / 64, NTOK / 128);     // 12 x 32
  dim3 g_hf(FFN_DIM / 64, NTOK / 128); // 48 x 32
  dim3 g_at(S_LEN / 64, NHEAD, 8);     // 8 x 12 x 8
  dim3 g_t1(HID / 32, HID / 32);       // 24 x 24
  dim3 g_t2(FFN_DIM / 32, HID / 32);   // 96 x 24
  dim3 g_t3(HID / 32, FFN_DIM / 32);   // 24 x 96
  dim3 g_vt(S_LEN / 32, HDIM / 32, 8 * NHEAD);

  const size_t WHH = (size_t)HID * HID;
  const size_t WHF = (size_t)HID * FFN_DIM;

  for (int l = 0; l < NLAYER; ++l) {
    size_t boff = (size_t)l * HID;
    // per-layer weight transpose+cvt into reused bf16 buffers
    tcvt_kernel<<<g_t1, blk, 0, stream>>>(wq + l * WHH, wT,           HID, HID);
    tcvt_kernel<<<g_t1, blk, 0, stream>>>(wk + l * WHH, wT + WHH,     HID, HID);
    tcvt_kernel<<<g_t1, blk, 0, stream>>>(wv + l * WHH, wT + 2 * WHH, HID, HID);
    tcvt_kernel<<<g_t1, blk, 0, stream>>>(wo + l * WHH, woT,          HID, HID);
    tcvt_kernel<<<g_t2, blk, 0, stream>>>(w1 + l * WHF, w1T, HID, FFN_DIM);
    tcvt_kernel<<<g_t3, blk, 0, stream>>>(w2 + l * WHF, w2T, FFN_DIM, HID);
    hipMemcpyAsync(qkvb,            bq + boff, HID * 4, hipMemcpyDeviceToDevice, stream);
    hipMemcpyAsync(qkvb + HID,      bk + boff, HID * 4, hipMemcpyDeviceToDevice, stream);
    hipMemcpyAsync(qkvb + 2 * HID,  bv + boff, HID * 4, hipMemcpyDeviceToDevice, stream);

    // fused QKV projection -> bf16 [tok][2304]
    mfma_gemm<1><<<g_qkv, blk, 0, stream>>>(h16, wT, qkvb, qkv16, NTOK, QKVN, HID);
    vtrans_kernel<<<g_vt, blk, 0, stream>>>(qkv16, vT16);
    attn_mfma<<<g_at, blk, 0, stream>>>(qkv16, vT16, mb, ctx16);
    mfma_gemm<0><<<g_hh, blk, 0, stream>>>(ctx16, woT, bo + boff, tmp32, NTOK, HID, HID);
    add_ln_kernel<<<dim3(NTOK), blk, 0, stream>>>(h32, tmp32, l1s + boff, l1b + boff, h32, h16);
    mfma_gemm<2><<<g_hf, blk, 0, stream>>>(h16, w1T, b1 + (size_t)l * FFN_DIM, ffn16,
                                           NTOK, FFN_DIM, HID);
    mfma_gemm<0><<<g_hh, blk, 0, stream>>>(ffn16, w2T, b2 + boff, tmp32, NTOK, HID, FFN_DIM);
    float* dst = (l == NLAYER - 1) ? (float*)d_out : h32;
    add_ln_kernel<<<dim3(NTOK), blk, 0, stream>>>(h32, tmp32, l2s + boff, l2b + boff, dst, h16);
  }
}

// Round 4
// 2883.294 us; speedup vs baseline: 6.2304x; 1.0810x over previous
//
#include <hip/hip_runtime.h>
#include <hip/hip_bf16.h>
#include <math.h>

// ---- problem constants (BERT-base, B=8, S=512) ----
#define S_LEN   512
#define HID     768
#define NLAYER  12
#define NHEAD   12
#define FFN_DIM 3072
#define HDIM    64
#define NTOK    4096   // B*S
#define QKVN    2304   // 3*HID

typedef __bf16 bf16x8 __attribute__((ext_vector_type(8)));
typedef float  f32x4  __attribute__((ext_vector_type(4)));
typedef unsigned short us8 __attribute__((ext_vector_type(8)));

typedef __attribute__((address_space(1))) const unsigned int gas_u32;
typedef __attribute__((address_space(3))) unsigned int las_u32;

#define MFMA16(a, b, c) __builtin_amdgcn_mfma_f32_16x16x32_bf16((a), (b), (c), 0, 0, 0)

// ---------------------------------------------------------------------------
// block-wide reduction of (sum, sumsq) over 256 threads (4 waves of 64)
// ---------------------------------------------------------------------------
__device__ __forceinline__ void block_reduce_2(float& sum, float& sq) {
  __shared__ float sd[8];
  int lane = threadIdx.x & 63;
  int wid  = threadIdx.x >> 6;
  #pragma unroll
  for (int off = 32; off > 0; off >>= 1) {
    sum += __shfl_down(sum, off, 64);
    sq  += __shfl_down(sq,  off, 64);
  }
  if (lane == 0) { sd[wid] = sum; sd[4 + wid] = sq; }
  __syncthreads();
  sum = sd[0] + sd[1] + sd[2] + sd[3];
  sq  = sd[4] + sd[5] + sd[6] + sd[7];
}

// ---------------------------------------------------------------------------
// mask bias: -10000 where input_id == 0 (padding), else 0
// ---------------------------------------------------------------------------
__global__ __launch_bounds__(256) void mask_kernel(const int* __restrict__ ids,
                                                   float* __restrict__ mb) {
  int i = blockIdx.x * 256 + threadIdx.x;
  if (i < NTOK) mb[i] = (ids[i] == 0) ? -10000.0f : 0.0f;
}

// ---------------------------------------------------------------------------
// pack q/k/v biases for ALL layers into [L][2304] once (kills 36 memcpys)
// ---------------------------------------------------------------------------
__global__ __launch_bounds__(256) void pack_qkvb_kernel(
    const float* __restrict__ bq, const float* __restrict__ bk,
    const float* __restrict__ bv, float* __restrict__ out) {
  int i = blockIdx.x * 256 + threadIdx.x;
  if (i >= NLAYER * QKVN) return;
  int l = i / QKVN, c = i % QKVN;
  float v = (c < HID) ? bq[l * HID + c]
          : (c < 2 * HID) ? bk[l * HID + c - HID]
                          : bv[l * HID + c - 2 * HID];
  out[i] = v;
}

// ---------------------------------------------------------------------------
// embeddings + layernorm -> fp32 h and bf16 h
// ---------------------------------------------------------------------------
__global__ __launch_bounds__(256) void embed_ln_kernel(
    const int* __restrict__ ids, const int* __restrict__ tids,
    const float* __restrict__ we, const float* __restrict__ pe,
    const float* __restrict__ te, const float* __restrict__ gamma,
    const float* __restrict__ beta, float* __restrict__ out32,
    __bf16* __restrict__ out16) {
  int t = blockIdx.x;
  int s = t & (S_LEN - 1);
  int id = ids[t];
  int tp = tids[t];
  float x[3];
  #pragma unroll
  for (int i = 0; i < 3; ++i) {
    int c = threadIdx.x + i * 256;
    x[i] = we[(size_t)id * HID + c] + pe[(size_t)s * HID + c] +
           te[(size_t)tp * HID + c];
  }
  float sum = x[0] + x[1] + x[2];
  float sq  = x[0]*x[0] + x[1]*x[1] + x[2]*x[2];
  block_reduce_2(sum, sq);
  float mu   = sum * (1.0f / HID);
  float var  = sq * (1.0f / HID) - mu * mu;
  float rstd = rsqrtf(var + 1e-12f);
  #pragma unroll
  for (int i = 0; i < 3; ++i) {
    int c = threadIdx.x + i * 256;
    float v = (x[i] - mu) * rstd * gamma[c] + beta[c];
    out32[(size_t)t * HID + c] = v;
    out16[(size_t)t * HID + c] = (__bf16)v;
  }
}

// ---------------------------------------------------------------------------
// residual add + layernorm -> fp32 (residual stream / d_out) and bf16 copy
// ---------------------------------------------------------------------------
__global__ __launch_bounds__(256) void add_ln_kernel(
    const float* __restrict__ a, const float* __restrict__ b,
    const float* __restrict__ gamma, const float* __restrict__ beta,
    float* __restrict__ out32, __bf16* __restrict__ out16) {
  int t = blockIdx.x;
  float x[3];
  #pragma unroll
  for (int i = 0; i < 3; ++i) {
    int c = threadIdx.x + i * 256;
    size_t idx = (size_t)t * HID + c;
    x[i] = a[idx] + b[idx];
  }
  float sum = x[0] + x[1] + x[2];
  float sq  = x[0]*x[0] + x[1]*x[1] + x[2]*x[2];
  block_reduce_2(sum, sq);
  float mu   = sum * (1.0f / HID);
  float var  = sq * (1.0f / HID) - mu * mu;
  float rstd = rsqrtf(var + 1e-12f);
  #pragma unroll
  for (int i = 0; i < 3; ++i) {
    int c = threadIdx.x + i * 256;
    float v = (x[i] - mu) * rstd * gamma[c] + beta[c];
    out32[(size_t)t * HID + c] = v;
    out16[(size_t)t * HID + c] = (__bf16)v;
  }
}

// ---------------------------------------------------------------------------
// transpose + fp32->bf16: src [R][C] f32 -> dst [C][R] bf16. R,C % 32 == 0.
// ---------------------------------------------------------------------------
__global__ __launch_bounds__(256) void tcvt_kernel(
    const float* __restrict__ src, __bf16* __restrict__ dst, int R, int C) {
  __shared__ float tile[32][33];
  int c0 = blockIdx.x * 32, r0 = blockIdx.y * 32;
  int tx = threadIdx.x & 31, ty = threadIdx.x >> 5;  // ty 0..7
  #pragma unroll
  for (int i = 0; i < 4; ++i) {
    int r = ty + i * 8;
    tile[r][tx] = src[(size_t)(r0 + r) * C + c0 + tx];
  }
  __syncthreads();
  #pragma unroll
  for (int i = 0; i < 4; ++i) {
    int r = ty + i * 8;
    dst[(size_t)(c0 + r) * R + r0 + tx] = (__bf16)tile[tx][r];
  }
}

// 4 HxH transposes (wq,wk,wv,wo) in one launch: blockIdx.z selects.
__global__ __launch_bounds__(256) void tcvt4_kernel(
    const float* __restrict__ s0, const float* __restrict__ s1,
    const float* __restrict__ s2, const float* __restrict__ s3,
    __bf16* __restrict__ d0, __bf16* __restrict__ d1,
    __bf16* __restrict__ d2, __bf16* __restrict__ d3) {
  __shared__ float tile[32][33];
  const float* src = (blockIdx.z == 0) ? s0 : (blockIdx.z == 1) ? s1
                   : (blockIdx.z == 2) ? s2 : s3;
  __bf16* dst = (blockIdx.z == 0) ? d0 : (blockIdx.z == 1) ? d1
              : (blockIdx.z == 2) ? d2 : d3;
  int c0 = blockIdx.x * 32, r0 = blockIdx.y * 32;
  int tx = threadIdx.x & 31, ty = threadIdx.x >> 5;
  #pragma unroll
  for (int i = 0; i < 4; ++i) {
    int r = ty + i * 8;
    tile[r][tx] = src[(size_t)(r0 + r) * HID + c0 + tx];
  }
  __syncthreads();
  #pragma unroll
  for (int i = 0; i < 4; ++i) {
    int r = ty + i * 8;
    dst[(size_t)(c0 + r) * HID + r0 + tx] = (__bf16)tile[tx][r];
  }
}

// ---------------------------------------------------------------------------
// V-transpose: qkv [tok][2304] (v at cols 1536..2303) -> vt [b][h][64][512]
// ---------------------------------------------------------------------------
__global__ __launch_bounds__(256) void vtrans_kernel(
    const __bf16* __restrict__ qkv, __bf16* __restrict__ vt) {
  __shared__ __bf16 tile[32][33];
  int bh = blockIdx.z;
  int b = bh / NHEAD, h = bh % NHEAD;
  int s0 = blockIdx.x * 32, d0 = blockIdx.y * 32;
  int tx = threadIdx.x & 31, ty = threadIdx.x >> 5;
  #pragma unroll
  for (int i = 0; i < 4; ++i) {
    int r = ty + i * 8;  // s
    tile[r][tx] = qkv[(size_t)(b * S_LEN + s0 + r) * QKVN + 2 * HID + h * HDIM + d0 + tx];
  }
  __syncthreads();
  #pragma unroll
  for (int i = 0; i < 4; ++i) {
    int r = ty + i * 8;  // d
    vt[((size_t)bh * HDIM + d0 + r) * S_LEN + s0 + tx] = tile[tx][r];
  }
}

// ---------------------------------------------------------------------------
// m97-style bf16 MFMA GEMM: C[M,N] = A[M,K] @ Bt[N,K]^T + bias.
// 128xTN tile (TN=128 or 64), BK=64, 256 threads.
//   TN=128: waves 2x2, each 64x64 (4x4 frags).  TN=64: waves 4x1, each 32x64.
// Staging: global_load_lds 16B, XOR swizzle on the GLOBAL source address
// (LDS dest is wave-uniform + lane*16), so frag ds_read_b128 is 2-way (free).
// MODE 0: f32 out; 1: bf16 out; 2: bf16 out + exact GELU.
// ---------------------------------------------------------------------------
template <int MODE, int TN>
__global__ __launch_bounds__(256) void mfma_gemm(
    const __bf16* __restrict__ A, const __bf16* __restrict__ Bt,
    const float* __restrict__ bias, void* __restrict__ Cout,
    int M, int N, int K) {
  constexpr int AI = 4;        // global_load_lds insts/wave for A (128 rows)
  constexpr int BI = TN / 32;  // and for B (TN rows)
  constexpr int RT = (TN == 128) ? 4 : 2;
  constexpr int CT = 4;
  __shared__ __align__(16) __bf16 As[128 * 64];
  __shared__ __align__(16) __bf16 Bs[TN * 64];
  const int tid = threadIdx.x;
  const int w = tid >> 6, lane = tid & 63;
  const int l15 = lane & 15, quad = lane >> 4;
  const int m0 = blockIdx.y * 128, n0 = blockIdx.x * TN;
  const int lr = lane >> 3;               // row-within-8 for staging
  const int colg = (lane & 7) ^ lr;       // swizzled global chunk column

  const int wr = (TN == 128) ? (w >> 1) * 64 : w * 32;  // wave row offset
  const int wc = (TN == 128) ? (w & 1) * 64 : 0;        // wave col offset

  f32x4 acc[RT][CT];
  const f32x4 z4 = {0.f, 0.f, 0.f, 0.f};
  #pragma unroll
  for (int i = 0; i < RT; ++i)
    #pragma unroll
    for (int j = 0; j < CT; ++j) acc[i][j] = z4;

  const __bf16* Ag = A  + (size_t)(m0 + 8 * AI * w + lr) * K + colg * 8;
  const __bf16* Bg = Bt + (size_t)(n0 + 8 * BI * w + lr) * K + colg * 8;
  __bf16* Al = As + 512 * AI * w;
  __bf16* Bl = Bs + 512 * BI * w;

  for (int kt = 0; kt < K; kt += 64) {
    #pragma unroll
    for (int i = 0; i < AI; ++i)
      __builtin_amdgcn_global_load_lds(
          (gas_u32*)(Ag + (size_t)(8 * i) * K + kt),
          (las_u32*)(Al + 512 * i), 16, 0, 0);
    #pragma unroll
    for (int i = 0; i < BI; ++i)
      __builtin_amdgcn_global_load_lds(
          (gas_u32*)(Bg + (size_t)(8 * i) * K + kt),
          (las_u32*)(Bl + 512 * i), 16, 0, 0);
    __syncthreads();
    #pragma unroll
    for (int kc = 0; kc < 2; ++kc) {
      bf16x8 af[RT], bfr[CT];
      #pragma unroll
      for (int rt = 0; rt < RT; ++rt) {
        int row = wr + rt * 16 + l15;
        af[rt] = *(const bf16x8*)&As[(row * 8 + ((kc * 4 + quad) ^ (row & 7))) * 8];
      }
      #pragma unroll
      for (int ct = 0; ct < CT; ++ct) {
        int col = wc + ct * 16 + l15;
        bfr[ct] = *(const bf16x8*)&Bs[(col * 8 + ((kc * 4 + quad) ^ (col & 7))) * 8];
      }
      #pragma unroll
      for (int rt = 0; rt < RT; ++rt)
        #pragma unroll
        for (int ct = 0; ct < CT; ++ct)
          acc[rt][ct] = MFMA16(af[rt], bfr[ct], acc[rt][ct]);
    }
    __syncthreads();
  }

  #pragma unroll
  for (int rt = 0; rt < RT; ++rt) {
    int rbase = m0 + wr + rt * 16 + quad * 4;
    #pragma unroll
    for (int ct = 0; ct < CT; ++ct) {
      int col = n0 + wc + ct * 16 + l15;
      float bv = bias[col];
      #pragma unroll
      for (int r = 0; r < 4; ++r) {
        float v = acc[rt][ct][r] + bv;
        if (MODE == 2) v = 0.5f * v * (1.0f + erff(v * 0.70710678118654752f));
        if (MODE == 0)
          ((float*)Cout)[(size_t)(rbase + r) * N + col] = v;
        else
          ((__bf16*)Cout)[(size_t)(rbase + r) * N + col] = (__bf16)v;
      }
    }
  }
}

// ---------------------------------------------------------------------------
// MFMA attention: block = (64 q-rows, head, batch); wave w owns 16 q-rows.
// ---------------------------------------------------------------------------
__global__ __launch_bounds__(256) void attn_mfma(
    const __bf16* __restrict__ qkv,  // [tok][2304], q at +0, k at +768
    const __bf16* __restrict__ vt,   // [b][h][64][512]
    const float* __restrict__ mb,    // [B*S]
    __bf16* __restrict__ ctx) {      // [tok][768]
  constexpr int PLD = 264;
  __shared__ __align__(16) __bf16 Plds[4][16 * PLD];
  const int tid = threadIdx.x;
  const int wv = tid >> 6, lane = tid & 63;
  const int l15 = lane & 15, quad = lane >> 4;
  const int b = blockIdx.z, hh = blockIdx.y, q0 = blockIdx.x * 64;
  const f32x4 z4 = {0.f, 0.f, 0.f, 0.f};

  size_t qoff = ((size_t)(b * S_LEN) + q0 + wv * 16 + l15) * QKVN + hh * HDIM;
  bf16x8 qa0 = *(const bf16x8*)(qkv + qoff + quad * 8);
  bf16x8 qa1 = *(const bf16x8*)(qkv + qoff + 32 + quad * 8);

  f32x4 sc[32];
  #pragma unroll
  for (int kt = 0; kt < 32; ++kt) {
    size_t koff = ((size_t)(b * S_LEN) + kt * 16 + l15) * QKVN + HID + hh * HDIM;
    bf16x8 kb0 = *(const bf16x8*)(qkv + koff + quad * 8);
    bf16x8 kb1 = *(const bf16x8*)(qkv + koff + 32 + quad * 8);
    f32x4 t = MFMA16(qa0, kb0, z4);
    sc[kt] = MFMA16(qa1, kb1, t);
  }

  float mx[4] = {-1e30f, -1e30f, -1e30f, -1e30f};
  #pragma unroll
  for (int kt = 0; kt < 32; ++kt) {
    float mval = mb[b * S_LEN + kt * 16 + l15];
    #pragma unroll
    for (int r = 0; r < 4; ++r) {
      float x = sc[kt][r] * 0.125f + mval;
      sc[kt][r] = x;
      mx[r] = fmaxf(mx[r], x);
    }
  }
  #pragma unroll
  for (int m = 1; m < 16; m <<= 1)
    #pragma unroll
    for (int r = 0; r < 4; ++r) mx[r] = fmaxf(mx[r], __shfl_xor(mx[r], m, 64));

  float sm[4] = {0.f, 0.f, 0.f, 0.f};
  #pragma unroll
  for (int kt = 0; kt < 32; ++kt)
    #pragma unroll
    for (int r = 0; r < 4; ++r) {
      float e = __expf(sc[kt][r] - mx[r]);
      sc[kt][r] = e;
      sm[r] += e;
    }
  #pragma unroll
  for (int m = 1; m < 16; m <<= 1)
    #pragma unroll
    for (int r = 0; r < 4; ++r) sm[r] += __shfl_xor(sm[r], m, 64);
  float inv[4];
  #pragma unroll
  for (int r = 0; r < 4; ++r) inv[r] = 1.0f / sm[r];

  __bf16* pbuf = &Plds[wv][0];
  const __bf16* vbase = vt + (size_t)(b * NHEAD + hh) * HDIM * S_LEN;
  f32x4 oc[4] = {z4, z4, z4, z4};
  #pragma unroll
  for (int half = 0; half < 2; ++half) {
    #pragma unroll
    for (int kt2 = 0; kt2 < 16; ++kt2) {
      int kt = half * 16 + kt2;
      #pragma unroll
      for (int r = 0; r < 4; ++r)
        pbuf[(quad * 4 + r) * PLD + kt2 * 16 + l15] = (__bf16)(sc[kt][r] * inv[r]);
    }
    #pragma unroll
    for (int kc = 0; kc < 8; ++kc) {
      bf16x8 pa = *(const bf16x8*)&pbuf[l15 * PLD + kc * 32 + quad * 8];
      int kbase = half * 256 + kc * 32;
      #pragma unroll
      for (int ct = 0; ct < 4; ++ct) {
        const __bf16* vp =
            vbase + (size_t)(ct * 16 + l15) * S_LEN + kbase + quad * 8;
        oc[ct] = MFMA16(pa, *(const bf16x8*)vp, oc[ct]);
      }
    }
  }

  int orow = b * S_LEN + q0 + wv * 16 + quad * 4;
  #pragma unroll
  for (int ct = 0; ct < 4; ++ct) {
    int col = hh * HDIM + ct * 16 + l15;
    #pragma unroll
    for (int r = 0; r < 4; ++r)
      ctx[(size_t)(orow + r) * HID + col] = (__bf16)oc[ct][r];
  }
}

// ---------------------------------------------------------------------------
// launch
// ---------------------------------------------------------------------------
extern "C" void kernel_launch(void* const* d_in, const int* in_sizes, int n_in,
                              void* d_out, int out_size, void* d_ws, size_t ws_size,
                              hipStream_t stream) {
  const int*   input_ids = (const int*)d_in[0];
  const int*   type_ids  = (const int*)d_in[1];
  const float* word_emb  = (const float*)d_in[2];
  const float* pos_emb   = (const float*)d_in[3];
  const float* type_emb  = (const float*)d_in[4];
  const float* eln_s     = (const float*)d_in[5];
  const float* eln_b     = (const float*)d_in[6];
  const float* wq = (const float*)d_in[7];
  const float* bq = (const float*)d_in[8];
  const float* wk = (const float*)d_in[9];
  const float* bk = (const float*)d_in[10];
  const float* wv = (const float*)d_in[11];
  const float* bv = (const float*)d_in[12];
  const float* wo = (const float*)d_in[13];
  const float* bo = (const float*)d_in[14];
  const float* l1s = (const float*)d_in[15];
  const float* l1b = (const float*)d_in[16];
  const float* w1  = (const float*)d_in[17];
  const float* b1  = (const float*)d_in[18];
  const float* w2  = (const float*)d_in[19];
  const float* b2  = (const float*)d_in[20];
  const float* l2s = (const float*)d_in[21];
  const float* l2b = (const float*)d_in[22];

  // ---- workspace carve-up (~71 MB) ----
  char* p = (char*)d_ws;
  float*   h32    = (float*)p;            p += (size_t)NTOK * HID * 4;
  float*   tmp32  = (float*)p;            p += (size_t)NTOK * HID * 4;
  __bf16*  vT16   = (__bf16*)tmp32;       // alias: vT live only during attn
  __bf16*  h16    = (__bf16*)p;           p += (size_t)NTOK * HID * 2;
  __bf16*  qkv16  = (__bf16*)p;           p += (size_t)NTOK * QKVN * 2;
  __bf16*  ctx16  = (__bf16*)p;           p += (size_t)NTOK * HID * 2;
  __bf16*  ffn16  = qkv16;                // alias qkv16+ctx16 contiguously
  __bf16*  wT     = (__bf16*)p;           p += (size_t)QKVN * HID * 2;
  __bf16*  woT    = (__bf16*)p;           p += (size_t)HID * HID * 2;
  __bf16*  w1T    = (__bf16*)p;           p += (size_t)HID * FFN_DIM * 2;
  __bf16*  w2T    = (__bf16*)p;           p += (size_t)HID * FFN_DIM * 2;
  float*   qkvb12 = (float*)p;            p += (size_t)NLAYER * QKVN * 4;
  float*   mb     = (float*)p;            p += (size_t)NTOK * 4;

  dim3 blk(256);
  mask_kernel<<<dim3(NTOK / 256), blk, 0, stream>>>(input_ids, mb);
  pack_qkvb_kernel<<<dim3((NLAYER * QKVN + 255) / 256), blk, 0, stream>>>(
      bq, bk, bv, qkvb12);
  embed_ln_kernel<<<dim3(NTOK), blk, 0, stream>>>(
      input_ids, type_ids, word_emb, pos_emb, type_emb, eln_s, eln_b, h32, h16);

  dim3 g_qkv(QKVN / 128, NTOK / 128);  // 18 x 32
  dim3 g_ff1(FFN_DIM / 128, NTOK / 128);  // 24 x 32
  dim3 g_h64(HID / 64, NTOK / 128);    // 12 x 32 (wo, ffn2: keeps >=256 blocks)
  dim3 g_at(S_LEN / 64, NHEAD, 8);     // 8 x 12 x 8
  dim3 g_t4(HID / 32, HID / 32, 4);    // fused 4x HxH transpose
  dim3 g_t2(FFN_DIM / 32, HID / 32);   // 96 x 24
  dim3 g_t3(HID / 32, FFN_DIM / 32);   // 24 x 96
  dim3 g_vt(S_LEN / 32, HDIM / 32, 8 * NHEAD);

  const size_t WHH = (size_t)HID * HID;
  const size_t WHF = (size_t)HID * FFN_DIM;

  for (int l = 0; l < NLAYER; ++l) {
    size_t boff = (size_t)l * HID;
    tcvt4_kernel<<<g_t4, blk, 0, stream>>>(
        wq + l * WHH, wk + l * WHH, wv + l * WHH, wo + l * WHH,
        wT, wT + WHH, wT + 2 * WHH, woT);
    tcvt_kernel<<<g_t2, blk, 0, stream>>>(w1 + l * WHF, w1T, HID, FFN_DIM);
    tcvt_kernel<<<g_t3, blk, 0, stream>>>(w2 + l * WHF, w2T, FFN_DIM, HID);

    mfma_gemm<1, 128><<<g_qkv, blk, 0, stream>>>(
        h16, wT, qkvb12 + (size_t)l * QKVN, qkv16, NTOK, QKVN, HID);
    vtrans_kernel<<<g_vt, blk, 0, stream>>>(qkv16, vT16);
    attn_mfma<<<g_at, blk, 0, stream>>>(qkv16, vT16, mb, ctx16);
    mfma_gemm<0, 64><<<g_h64, blk, 0, stream>>>(
        ctx16, woT, bo + boff, tmp32, NTOK, HID, HID);
    add_ln_kernel<<<dim3(NTOK), blk, 0, stream>>>(
        h32, tmp32, l1s + boff, l1b + boff, h32, h16);
    mfma_gemm<2, 128><<<g_ff1, blk, 0, stream>>>(
        h16, w1T, b1 + (size_t)l * FFN_DIM, ffn16, NTOK, FFN_DIM, HID);
    mfma_gemm<0, 64><<<g_h64, blk, 0, stream>>>(
        ffn16, w2T, b2 + boff, tmp32, NTOK, HID, FFN_DIM);
    float* dst = (l == NLAYER - 1) ? (float*)d_out : h32;
    add_ln_kernel<<<dim3(NTOK), blk, 0, stream>>>(
        h32, tmp32, l2s + boff, l2b + boff, dst, h16);
  }
}